// Round 3
// baseline (275.055 us; speedup 1.0000x reference)
//
#include <hip/hip_runtime.h>
#include <math.h>

typedef unsigned short ushort_t;
typedef __bf16 bf16x8 __attribute__((ext_vector_type(8)));
typedef ushort_t ushort8v __attribute__((ext_vector_type(8)));
typedef float f32x4 __attribute__((ext_vector_type(4)));

#define B_SZ   4
#define SEQ    8192
#define M_ROWS (B_SZ * SEQ)   // 32768
#define CH     128
#define NC     (SEQ / CH)     // 64

__device__ __forceinline__ ushort_t f2bf(float f) {
    unsigned u = __float_as_uint(f);
    u = u + 0x7fffu + ((u >> 16) & 1u);
    return (ushort_t)(u >> 16);
}
__device__ __forceinline__ float bf2f(ushort_t b) {
    return __uint_as_float(((unsigned)b) << 16);
}

__device__ __forceinline__ void load16_lds(const void* g, void* l) {
    __builtin_amdgcn_global_load_lds(
        (const __attribute__((address_space(1))) unsigned int*)g,
        (__attribute__((address_space(3))) unsigned int*)l, 16, 0, 0);
}

__device__ __forceinline__ bf16x8 ldfrag(const ushort_t* p) {
    union { ushort8v u; bf16x8 b; } cv;
    cv.u = *(const ushort8v*)p;
    return cv.b;
}

// ---------------------------------------------------------------------------
// prep / conv_x unchanged.
__global__ void prep_kernel(const float* __restrict__ Lre,
                            const float* __restrict__ Lim,
                            const float* __restrict__ ldt,
                            const float* __restrict__ Bre,
                            const float* __restrict__ Bim,
                            const float* __restrict__ Cre,
                            const float* __restrict__ Cim,
                            float* __restrict__ abar,
                            float* __restrict__ apow,
                            ushort_t* __restrict__ Bmat,
                            ushort_t* __restrict__ Cmat) {
    int idx = blockIdx.x * 256 + threadIdx.x;   // 0 .. 262143
    int h = idx & 511;
    int p = (idx >> 9) & 255;
    int d = idx >> 17;
    int ip = d * 256 + p;
    float lr = Lre[ip], li = Lim[ip];
    float dt = expf(ldt[ip]);
    float e   = expf(lr * dt);
    float ang = li * dt;
    float ar = e * cosf(ang), ai = e * sinf(ang);
    float nr = ar - 1.0f, ni = ai;
    float den = lr * lr + li * li;
    float cr = (nr * lr + ni * li) / den;
    float ci = (ni * lr - nr * li) / den;
    float br = Bre[idx], bi = Bim[idx];
    Bmat[(d * 512 + 2 * p) * 512 + h]     = f2bf(cr * br - ci * bi);
    Bmat[(d * 512 + 2 * p + 1) * 512 + h] = f2bf(cr * bi + ci * br);
    if (h == 0) {
        int o = d * 512 + 2 * p;
        abar[o] = ar;  abar[o + 1] = ai;
        float eC = expf(lr * dt * (float)CH);
        float aC = ang * (float)CH;
        apow[o] = eC * cosf(aC);  apow[o + 1] = eC * sinf(aC);
    }
    int p2 = idx & 255;
    int h2 = (idx >> 8) & 511;
    int d2 = idx >> 17;
    Cmat[h2 * 1024 + d2 * 512 + 2 * p2]     = f2bf(Cre[idx]);
    Cmat[h2 * 1024 + d2 * 512 + 2 * p2 + 1] = f2bf(-Cim[idx]);
}

__global__ void conv_x_kernel(const float* __restrict__ x,
                              ushort_t* __restrict__ X16) {
    int i = blockIdx.x * 256 + threadIdx.x;
    float4 v = ((const float4*)x)[i];
    ushort_t o[4] = {f2bf(v.x), f2bf(v.y), f2bf(v.z), f2bf(v.w)};
    *(uint2*)&X16[(size_t)i * 4] = *(const uint2*)o;
}

// ---------------------------------------------------------------------------
// 256x256 8-phase bf16 GEMM (T2+T3+T4+T5) with NPAIR persistent m-tiles per
// block.  NPAIR=2 (GEMM1): grid 256, each block runs m-tiles {2mp,2mp+1}
// back-to-back in ONE continuous pipeline; staging indices run past NKT into
// the next m-tile; a mid-loop epilogue dumps+zeroes acc between tiles while
// tile-2 prefetches are in flight.  Mid-epilogue stores enter the vmcnt FIFO,
// so the next boundary vmcnt(6) also drains them (~3-4us, still net ahead of
// a full second-generation prologue+refill).
// Steady-state slot schedule (verified): A(t,0)<-kt=t-2 ph2; B(t,0)<-t-2 ph3;
// A(t,1)<-t-2 ph4; B(t,1)<-t-1 ph1.  At each tile boundary the newest 6
// outstanding loads are tile t+2's A0,B0,A1 -> vmcnt(6) guarantees tile t+1
// fully staged.  Never vmcnt(0) in the main loop.
template<int EPI, int KD_, int NT, int NPAIR>
__global__ __launch_bounds__(512, 2)
void gemm_8ph(const ushort_t* __restrict__ A, const ushort_t* __restrict__ Bm,
              ushort_t* __restrict__ Cb, float* __restrict__ Cf,
              const float* __restrict__ X, const float* __restrict__ Dv) {
    __shared__ ushort_t shA[2][2][256 * 32];
    __shared__ ushort_t shB[2][2][256 * 32];
    constexpr int NKT    = KD_ / 64;          // K-tiles per m-tile
    constexpr int TT     = NKT * NPAIR;       // total staged tiles
    constexpr int LOGNKT = (KD_ == 512) ? 3 : 4;

    const int tid  = threadIdx.x;
    const int lane = tid & 63;
    const int wv   = tid >> 6;
    const int wr = wv >> 2, wc = wv & 3;
    const int l15 = lane & 15, lq = lane >> 4;

    // XCD swizzle: all NT n-tiles of an m-pair adjacent on one XCD.
    const int lin = blockIdx.x;
    const int xcd = lin & 7;
    const int j   = lin >> 3;
    const int mp  = xcd * (16 / NPAIR) + j / NT;
    const int nt  = j % NT;
    const int m0 = mp * 256 * NPAIR;
    const int n0 = nt * 256;
    const int CN = NT * 256;

    f32x4 acc[8][4];
#pragma unroll
    for (int i = 0; i < 8; ++i)
#pragma unroll
        for (int jj = 0; jj < 4; ++jj)
            acc[i][jj] = (f32x4){0.f, 0.f, 0.f, 0.f};

    // staging: thread -> (row, chunk); LDS dest linear, global src pre-swizzled.
    const int srow = wv * 32 + (lane >> 2);
    const int sck  = (((lane & 3) ^ ((lane >> 3) & 3))) * 8;
    const ushort_t* Ag = A  + (size_t)(m0 + srow) * KD_ + sck;
    const ushort_t* Bg = Bm + (size_t)(n0 + srow) * KD_ + sck;

#define STAGE_A(t, ks) do {                                                   \
        const ushort_t* g_ = Ag                                               \
            + (NPAIR > 1 ? (size_t)((t) >> LOGNKT) * (256u * KD_) : 0)        \
            + (size_t)((t) & (NKT - 1)) * 64 + (ks) * 32;                     \
        ushort_t* d_ = &shA[(t) & 1][(ks)][wv * 1024];                        \
        load16_lds(g_, d_);                                                   \
        load16_lds(g_ + (size_t)16 * KD_, d_ + 512);                          \
    } while (0)
#define STAGE_B(t, ks) do {                                                   \
        const ushort_t* g_ = Bg + (size_t)((t) & (NKT - 1)) * 64 + (ks) * 32; \
        ushort_t* d_ = &shB[(t) & 1][(ks)][wv * 1024];                        \
        load16_lds(g_, d_);                                                   \
        load16_lds(g_ + (size_t)16 * KD_, d_ + 512);                          \
    } while (0)

    const int rdoff = ((lq ^ ((l15 >> 1) & 3))) * 8;
    const int rdA = (wr * 128 + l15) * 32 + rdoff;
    const int rdB = (wc * 64  + l15) * 32 + rdoff;

#define MFMA_PH(bx, by, nlo) do {                                             \
        __builtin_amdgcn_s_setprio(1);                                        \
        _Pragma("unroll")                                                     \
        for (int mi_ = 0; mi_ < 8; ++mi_) {                                   \
            acc[mi_][nlo]     = __builtin_amdgcn_mfma_f32_16x16x32_bf16(      \
                af[mi_], bx, acc[mi_][nlo], 0, 0, 0);                         \
            acc[mi_][nlo + 1] = __builtin_amdgcn_mfma_f32_16x16x32_bf16(      \
                af[mi_], by, acc[mi_][nlo + 1], 0, 0, 0);                     \
        }                                                                     \
        __builtin_amdgcn_s_setprio(0);                                        \
    } while (0)

#define EPILOGUE(TB) do {                                                     \
        _Pragma("unroll")                                                     \
        for (int mi = 0; mi < 8; ++mi) {                                      \
            _Pragma("unroll")                                                 \
            for (int ni = 0; ni < 4; ++ni) {                                  \
                const int col = n0 + wc * 64 + ni * 16 + l15;                 \
                float dsum = 0.f;                                             \
                if (EPI == 1) dsum = Dv[col] + Dv[512 + col];                 \
                _Pragma("unroll")                                             \
                for (int r = 0; r < 4; ++r) {                                 \
                    const int row = m0 + (TB) * 256 + wr * 128 + mi * 16      \
                                    + lq * 4 + r;                             \
                    if (EPI == 0) {                                           \
                        Cb[(size_t)row * CN + col] = f2bf(acc[mi][ni][r]);    \
                    } else {                                                  \
                        const size_t idx = (size_t)row * 512 + col;           \
                        Cf[idx] = acc[mi][ni][r] + X[idx] * dsum;             \
                    }                                                         \
                }                                                             \
            }                                                                 \
        }                                                                     \
    } while (0)

    // prologue: tile0 + {A(1,0), B(1,0), A(1,1)}; vmcnt(6) -> tile0 landed.
    STAGE_A(0, 0); STAGE_A(0, 1); STAGE_B(0, 0); STAGE_B(0, 1);
    STAGE_A(1, 0); STAGE_B(1, 0); STAGE_A(1, 1);
    asm volatile("s_waitcnt vmcnt(6)" ::: "memory");
    __builtin_amdgcn_s_barrier();

    bf16x8 af[8];
#pragma unroll 2
    for (int kt = 0; kt < TT; ++kt) {
        const int buf = kt & 1;
        const ushort_t* aS0 = &shA[buf][0][rdA];
        const ushort_t* aS1 = &shA[buf][1][rdA];
        const ushort_t* bS0 = &shB[buf][0][rdB];
        const ushort_t* bS1 = &shB[buf][1][rdB];

        { // phase 1: ks0 x ni{0,1}
#pragma unroll
            for (int mi = 0; mi < 8; ++mi) af[mi] = ldfrag(aS0 + mi * 512);
            bf16x8 b0 = ldfrag(bS0), b1 = ldfrag(bS0 + 512);
            if (kt + 1 < TT) STAGE_B(kt + 1, 1);
            __builtin_amdgcn_s_barrier();
            MFMA_PH(b0, b1, 0);
            __builtin_amdgcn_s_barrier();
        }
        { // phase 2: ks0 x ni{2,3}
            bf16x8 b2 = ldfrag(bS0 + 1024), b3 = ldfrag(bS0 + 1536);
            if (kt + 2 < TT) STAGE_A(kt + 2, 0);
            __builtin_amdgcn_s_barrier();
            MFMA_PH(b2, b3, 2);
            __builtin_amdgcn_s_barrier();
        }
        { // phase 3: ks1 x ni{0,1}
#pragma unroll
            for (int mi = 0; mi < 8; ++mi) af[mi] = ldfrag(aS1 + mi * 512);
            bf16x8 b0 = ldfrag(bS1), b1 = ldfrag(bS1 + 512);
            if (kt + 2 < TT) STAGE_B(kt + 2, 0);
            __builtin_amdgcn_s_barrier();
            MFMA_PH(b0, b1, 0);
            __builtin_amdgcn_s_barrier();
        }
        { // phase 4: ks1 x ni{2,3} + tile boundary
            bf16x8 b2 = ldfrag(bS1 + 1024), b3 = ldfrag(bS1 + 1536);
            if (kt + 2 < TT) STAGE_A(kt + 2, 1);
            __builtin_amdgcn_s_barrier();
            MFMA_PH(b2, b3, 2);
            if (kt + 1 < TT) {
                if (kt + 2 < TT)
                    asm volatile("s_waitcnt vmcnt(6)" ::: "memory");
                else
                    asm volatile("s_waitcnt vmcnt(0)" ::: "memory");
                __builtin_amdgcn_s_barrier();
            }
        }
        // mid-pair epilogue: dump tile-1 acc while tile-2 staging is in flight
        if (NPAIR == 2 && kt == NKT - 1) {
            EPILOGUE(0);
#pragma unroll
            for (int i2 = 0; i2 < 8; ++i2)
#pragma unroll
                for (int j2 = 0; j2 < 4; ++j2)
                    acc[i2][j2] = (f32x4){0.f, 0.f, 0.f, 0.f};
        }
    }
#undef STAGE_A
#undef STAGE_B
#undef MFMA_PH

    EPILOGUE(NPAIR - 1);
#undef EPILOGUE
}

// ---------------------------------------------------------------------------
// scan_carry unchanged (known good).
__global__ __launch_bounds__(512)
void scan_carry(const ushort_t* __restrict__ S, const float* __restrict__ abar,
                float* __restrict__ carry) {
    int b = blockIdx.x, c = blockIdx.y, t = threadIdx.x;
    int dir = t >> 8, p = t & 255;
    float ar = abar[dir * 512 + 2 * p], ai = abar[dir * 512 + 2 * p + 1];
    float sr = 0.f, si = 0.f;
    const ushort_t* base = S + ((size_t)b * SEQ + (size_t)c * CH) * 1024
                             + dir * 512 + 2 * p;
    for (int ii = 0; ii < CH; ++ii) {
        int i = dir ? (CH - 1 - ii) : ii;
        unsigned u = *(const unsigned*)(base + (size_t)i * 1024);
        float re = bf2f((ushort_t)(u & 0xffffu));
        float im = bf2f((ushort_t)(u >> 16));
        float nr = fmaf(ar, sr, fmaf(-ai, si, re));
        float ni = fmaf(ar, si, fmaf(ai, sr, im));
        sr = nr; si = ni;
    }
    int o = (b * NC + c) * 1024 + dir * 512 + 2 * p;
    carry[o] = sr; carry[o + 1] = si;
}

// ---------------------------------------------------------------------------
// scan_fin2 = scan_comb folded into scan_final (NON-cooperative).  Each (b,c)
// block rebuilds its own exclusive chunk-prefix from the carry array (<=63
// L2-hot complex FMAs, bit-identical fold order to the old scan_comb), then
// applies the final in-place pass.  Removes the 4-block parallelism-starved
// scan_comb dispatch.  dir is wave-uniform (t>>8) -> no divergence.
__global__ __launch_bounds__(512)
void scan_fin2(ushort_t* __restrict__ S, const float* __restrict__ abar,
               const float* __restrict__ apow, const float* __restrict__ carry) {
    int b = blockIdx.x, c = blockIdx.y, t = threadIdx.x;
    int dir = t >> 8, p = t & 255;
    float ar = abar[dir * 512 + 2 * p], ai = abar[dir * 512 + 2 * p + 1];
    float pr = apow[dir * 512 + 2 * p], pi = apow[dir * 512 + 2 * p + 1];
    float sr = 0.f, si = 0.f;
    if (dir == 0) {
        for (int cc = 0; cc < c; ++cc) {
            int o = (b * NC + cc) * 1024 + 2 * p;
            float cr0 = carry[o], ci0 = carry[o + 1];
            float nr = fmaf(pr, sr, fmaf(-pi, si, cr0));
            float ni = fmaf(pr, si, fmaf(pi, sr, ci0));
            sr = nr; si = ni;
        }
    } else {
        for (int cc = NC - 1; cc > c; --cc) {
            int o = (b * NC + cc) * 1024 + 512 + 2 * p;
            float cr0 = carry[o], ci0 = carry[o + 1];
            float nr = fmaf(pr, sr, fmaf(-pi, si, cr0));
            float ni = fmaf(pr, si, fmaf(pi, sr, ci0));
            sr = nr; si = ni;
        }
    }
    ushort_t* base = S + ((size_t)b * SEQ + (size_t)c * CH) * 1024
                       + dir * 512 + 2 * p;
    for (int ii = 0; ii < CH; ++ii) {
        int i = dir ? (CH - 1 - ii) : ii;
        unsigned* addr = (unsigned*)(base + (size_t)i * 1024);
        unsigned u = *addr;
        float re = bf2f((ushort_t)(u & 0xffffu));
        float im = bf2f((ushort_t)(u >> 16));
        float nr = fmaf(ar, sr, fmaf(-ai, si, re));
        float ni = fmaf(ar, si, fmaf(ai, sr, im));
        sr = nr; si = ni;
        *addr = ((unsigned)f2bf(si) << 16) | (unsigned)f2bf(sr);
    }
}

// ---------------------------------------------------------------------------
// ws layout (bytes):
//  SB16 : 0           (67,108,864)  [M][1024] bf16 states both dirs
//  X16  : 67,108,864  (33,554,432)  bf16 x
//  Bm16 : 100,663,296 (1,048,576)
//  Cm16 : 101,711,872 (1,048,576)
//  abar : 102,760,448 (4,096)
//  apow : 102,764,544 (4,096)
//  carry: 67,108,864  (1,048,576)   alias over X16 head (dead after GEMM1)
extern "C" void kernel_launch(void* const* d_in, const int* in_sizes, int n_in,
                              void* d_out, int out_size, void* d_ws, size_t ws_size,
                              hipStream_t stream) {
    const float* x   = (const float*)d_in[0];
    const float* Lre = (const float*)d_in[1];
    const float* Lim = (const float*)d_in[2];
    const float* ldt = (const float*)d_in[3];
    const float* Bre = (const float*)d_in[4];
    const float* Bim = (const float*)d_in[5];
    const float* Cre = (const float*)d_in[6];
    const float* Cim = (const float*)d_in[7];
    const float* Dv  = (const float*)d_in[8];
    float* y = (float*)d_out;
    char* ws = (char*)d_ws;

    ushort_t* SB16 = (ushort_t*)(ws);
    ushort_t* X16  = (ushort_t*)(ws + 67108864);
    ushort_t* Bm16 = (ushort_t*)(ws + 100663296);
    ushort_t* Cm16 = (ushort_t*)(ws + 101711872);
    float* abar  = (float*)(ws + 102760448);
    float* apow  = (float*)(ws + 102764544);
    float* carry = (float*)(ws + 67108864);

    prep_kernel<<<1024, 256, 0, stream>>>(Lre, Lim, ldt, Bre, Bim, Cre, Cim,
                                          abar, apow, Bm16, Cm16);
    conv_x_kernel<<<16384, 256, 0, stream>>>(x, X16);

    // GEMM1: SB[M][1024] = X16[M][512] * Bm16[1024][512]^T
    // 256 blocks, each runs 2 m-tiles persistently (64 mp x 4 nt).
    gemm_8ph<0, 512, 4, 2><<<256, 512, 0, stream>>>(X16, Bm16, SB16, nullptr,
                                                    nullptr, nullptr);

    dim3 gs(B_SZ, NC);
    scan_carry<<<gs, 512, 0, stream>>>(SB16, abar, carry);
    scan_fin2<<<gs, 512, 0, stream>>>(SB16, abar, apow, carry);

    // GEMM2: y[M][512] = SB16[M][1024] * Cm16[512][1024]^T + x*(D0+D1)
    gemm_8ph<1, 1024, 2, 1><<<256, 512, 0, stream>>>(SB16, Cm16, nullptr, y,
                                                     x, Dv);
}

// Round 4
// 271.747 us; speedup vs baseline: 1.0122x; 1.0122x over previous
//
#include <hip/hip_runtime.h>
#include <math.h>

typedef unsigned short ushort_t;
typedef __bf16 bf16x8 __attribute__((ext_vector_type(8)));
typedef ushort_t ushort8v __attribute__((ext_vector_type(8)));
typedef float f32x4 __attribute__((ext_vector_type(4)));

#define B_SZ   4
#define SEQ    8192
#define M_ROWS (B_SZ * SEQ)   // 32768
#define CH     128
#define NC     (SEQ / CH)     // 64

__device__ __forceinline__ ushort_t f2bf(float f) {
    unsigned u = __float_as_uint(f);
    u = u + 0x7fffu + ((u >> 16) & 1u);
    return (ushort_t)(u >> 16);
}
__device__ __forceinline__ float bf2f(ushort_t b) {
    return __uint_as_float(((unsigned)b) << 16);
}

__device__ __forceinline__ void load16_lds(const void* g, void* l) {
    __builtin_amdgcn_global_load_lds(
        (const __attribute__((address_space(1))) unsigned int*)g,
        (__attribute__((address_space(3))) unsigned int*)l, 16, 0, 0);
}

__device__ __forceinline__ bf16x8 ldfrag(const ushort_t* p) {
    union { ushort8v u; bf16x8 b; } cv;
    cv.u = *(const ushort8v*)p;
    return cv.b;
}

__device__ __forceinline__ float2 cmul(float2 a, float2 b) {
    return make_float2(a.x * b.x - a.y * b.y, a.x * b.y + a.y * b.x);
}

// ---------------------------------------------------------------------------
// prep: unchanged except it now ALSO writes PW[q][6] = {a, a^4, a^16} (complex)
// for the fused in-epilogue carry computation (q = d*256+p = col>>1).
__global__ void prep_kernel(const float* __restrict__ Lre,
                            const float* __restrict__ Lim,
                            const float* __restrict__ ldt,
                            const float* __restrict__ Bre,
                            const float* __restrict__ Bim,
                            const float* __restrict__ Cre,
                            const float* __restrict__ Cim,
                            float* __restrict__ abar,
                            float* __restrict__ apow,
                            float* __restrict__ PW,
                            ushort_t* __restrict__ Bmat,
                            ushort_t* __restrict__ Cmat) {
    int idx = blockIdx.x * 256 + threadIdx.x;   // 0 .. 262143
    int h = idx & 511;
    int p = (idx >> 9) & 255;
    int d = idx >> 17;
    int ip = d * 256 + p;
    float lr = Lre[ip], li = Lim[ip];
    float dt = expf(ldt[ip]);
    float e   = expf(lr * dt);
    float ang = li * dt;
    float ar = e * cosf(ang), ai = e * sinf(ang);
    float nr = ar - 1.0f, ni = ai;
    float den = lr * lr + li * li;
    float cr = (nr * lr + ni * li) / den;
    float ci = (ni * lr - nr * li) / den;
    float br = Bre[idx], bi = Bim[idx];
    Bmat[(d * 512 + 2 * p) * 512 + h]     = f2bf(cr * br - ci * bi);
    Bmat[(d * 512 + 2 * p + 1) * 512 + h] = f2bf(cr * bi + ci * br);
    if (h == 0) {
        int o = d * 512 + 2 * p;
        abar[o] = ar;  abar[o + 1] = ai;
        float eC = expf(lr * dt * (float)CH);
        float aC = ang * (float)CH;
        apow[o] = eC * cosf(aC);  apow[o + 1] = eC * sinf(aC);
        // power table for fused carry: a, a^4, a^16
        float2 a1 = make_float2(ar, ai);
        float2 a2 = cmul(a1, a1);
        float2 a4 = cmul(a2, a2);
        float2 a8 = cmul(a4, a4);
        float2 a16 = cmul(a8, a8);
        int q = d * 256 + p;
        PW[q * 6 + 0] = a1.x;  PW[q * 6 + 1] = a1.y;
        PW[q * 6 + 2] = a4.x;  PW[q * 6 + 3] = a4.y;
        PW[q * 6 + 4] = a16.x; PW[q * 6 + 5] = a16.y;
    }
    int p2 = idx & 255;
    int h2 = (idx >> 8) & 511;
    int d2 = idx >> 17;
    Cmat[h2 * 1024 + d2 * 512 + 2 * p2]     = f2bf(Cre[idx]);
    Cmat[h2 * 1024 + d2 * 512 + 2 * p2 + 1] = f2bf(-Cim[idx]);
}

__global__ void conv_x_kernel(const float* __restrict__ x,
                              ushort_t* __restrict__ X16) {
    int i = blockIdx.x * 256 + threadIdx.x;
    float4 v = ((const float4*)x)[i];
    ushort_t o[4] = {f2bf(v.x), f2bf(v.y), f2bf(v.z), f2bf(v.w)};
    *(uint2*)&X16[(size_t)i * 4] = *(const uint2*)o;
}

// ---------------------------------------------------------------------------
// 256x256 8-phase bf16 GEMM (T2+T3+T4+T5), Round-1 structure (NPAIR reverted:
// measured regression).  NEW for EPI==0: fused chunk-carry in the epilogue.
// Each wave-row wr owns exactly one 128-row chunk (rows m0+wr*128..+127);
// carry[chunk][col] = sum_k a^(e) * bu[k], e = 127-k (dir0) or k (dir1),
// k = mi*16+lq*4+r.  Decompose a^e = (a^16)^s * (a^4)^lqp * a^rp with all
// exponents per-lane static (dir is block-uniform, loops unrolled).  re/im
// partners exchanged via shfl_xor(1); lq-reduce via shfl_xor 16/32.
// Values use bf2f(f2bf(acc)) to match what scan_carry read from SB.
// carry lives in d_out (dead until GEMM2; stream-ordered safe) -- it must NOT
// alias X16, which is GEMM1's live A operand.
template<int EPI, int KD_, int NT>
__global__ __launch_bounds__(512, 2)
void gemm_8ph(const ushort_t* __restrict__ A, const ushort_t* __restrict__ Bm,
              ushort_t* __restrict__ Cb, float* __restrict__ Cf,
              const float* __restrict__ X, const float* __restrict__ Dv,
              const float* __restrict__ PW, float* __restrict__ CAR) {
    __shared__ ushort_t shA[2][2][256 * 32];
    __shared__ ushort_t shB[2][2][256 * 32];
    constexpr int NKT = KD_ / 64;

    const int tid  = threadIdx.x;
    const int lane = tid & 63;
    const int wv   = tid >> 6;
    const int wr = wv >> 2, wc = wv & 3;
    const int l15 = lane & 15, lq = lane >> 4;

    const int lin = blockIdx.x;
    const int xcd = lin & 7;
    const int j   = lin >> 3;
    const int mt  = xcd * 16 + j / NT;
    const int nt  = j % NT;
    const int m0 = mt * 256;
    const int n0 = nt * 256;
    const int CN = NT * 256;

    f32x4 acc[8][4];
#pragma unroll
    for (int i = 0; i < 8; ++i)
#pragma unroll
        for (int jj = 0; jj < 4; ++jj)
            acc[i][jj] = (f32x4){0.f, 0.f, 0.f, 0.f};

    const int srow = wv * 32 + (lane >> 2);
    const int sck  = (((lane & 3) ^ ((lane >> 3) & 3))) * 8;
    const ushort_t* Ag = A  + (size_t)(m0 + srow) * KD_ + sck;
    const ushort_t* Bg = Bm + (size_t)(n0 + srow) * KD_ + sck;

#define STAGE_A(t, ks) do {                                                   \
        const ushort_t* g_ = Ag + (size_t)(t) * 64 + (ks) * 32;               \
        ushort_t* d_ = &shA[(t) & 1][(ks)][wv * 1024];                        \
        load16_lds(g_, d_);                                                   \
        load16_lds(g_ + (size_t)16 * KD_, d_ + 512);                          \
    } while (0)
#define STAGE_B(t, ks) do {                                                   \
        const ushort_t* g_ = Bg + (size_t)(t) * 64 + (ks) * 32;               \
        ushort_t* d_ = &shB[(t) & 1][(ks)][wv * 1024];                        \
        load16_lds(g_, d_);                                                   \
        load16_lds(g_ + (size_t)16 * KD_, d_ + 512);                          \
    } while (0)

    const int rdoff = ((lq ^ ((l15 >> 1) & 3))) * 8;
    const int rdA = (wr * 128 + l15) * 32 + rdoff;
    const int rdB = (wc * 64  + l15) * 32 + rdoff;

#define MFMA_PH(bx, by, nlo) do {                                             \
        __builtin_amdgcn_s_setprio(1);                                        \
        _Pragma("unroll")                                                     \
        for (int mi_ = 0; mi_ < 8; ++mi_) {                                   \
            acc[mi_][nlo]     = __builtin_amdgcn_mfma_f32_16x16x32_bf16(      \
                af[mi_], bx, acc[mi_][nlo], 0, 0, 0);                         \
            acc[mi_][nlo + 1] = __builtin_amdgcn_mfma_f32_16x16x32_bf16(      \
                af[mi_], by, acc[mi_][nlo + 1], 0, 0, 0);                     \
        }                                                                     \
        __builtin_amdgcn_s_setprio(0);                                        \
    } while (0)

    STAGE_A(0, 0); STAGE_A(0, 1); STAGE_B(0, 0); STAGE_B(0, 1);
    STAGE_A(1, 0); STAGE_B(1, 0); STAGE_A(1, 1);
    asm volatile("s_waitcnt vmcnt(6)" ::: "memory");
    __builtin_amdgcn_s_barrier();

    bf16x8 af[8];
#pragma unroll 2
    for (int kt = 0; kt < NKT; ++kt) {
        const int buf = kt & 1;
        const ushort_t* aS0 = &shA[buf][0][rdA];
        const ushort_t* aS1 = &shA[buf][1][rdA];
        const ushort_t* bS0 = &shB[buf][0][rdB];
        const ushort_t* bS1 = &shB[buf][1][rdB];

        { // phase 1: ks0 x ni{0,1}
#pragma unroll
            for (int mi = 0; mi < 8; ++mi) af[mi] = ldfrag(aS0 + mi * 512);
            bf16x8 b0 = ldfrag(bS0), b1 = ldfrag(bS0 + 512);
            if (kt + 1 < NKT) STAGE_B(kt + 1, 1);
            __builtin_amdgcn_s_barrier();
            MFMA_PH(b0, b1, 0);
            __builtin_amdgcn_s_barrier();
        }
        { // phase 2: ks0 x ni{2,3}
            bf16x8 b2 = ldfrag(bS0 + 1024), b3 = ldfrag(bS0 + 1536);
            if (kt + 2 < NKT) STAGE_A(kt + 2, 0);
            __builtin_amdgcn_s_barrier();
            MFMA_PH(b2, b3, 2);
            __builtin_amdgcn_s_barrier();
        }
        { // phase 3: ks1 x ni{0,1}
#pragma unroll
            for (int mi = 0; mi < 8; ++mi) af[mi] = ldfrag(aS1 + mi * 512);
            bf16x8 b0 = ldfrag(bS1), b1 = ldfrag(bS1 + 512);
            if (kt + 2 < NKT) STAGE_B(kt + 2, 0);
            __builtin_amdgcn_s_barrier();
            MFMA_PH(b0, b1, 0);
            __builtin_amdgcn_s_barrier();
        }
        { // phase 4: ks1 x ni{2,3} + tile boundary
            bf16x8 b2 = ldfrag(bS1 + 1024), b3 = ldfrag(bS1 + 1536);
            if (kt + 2 < NKT) STAGE_A(kt + 2, 1);
            __builtin_amdgcn_s_barrier();
            MFMA_PH(b2, b3, 2);
            if (kt + 1 < NKT) {
                if (kt + 2 < NKT)
                    asm volatile("s_waitcnt vmcnt(6)" ::: "memory");
                else
                    asm volatile("s_waitcnt vmcnt(0)" ::: "memory");
                __builtin_amdgcn_s_barrier();
            }
        }
    }
#undef STAGE_A
#undef STAGE_B
#undef MFMA_PH

    // ---- store epilogue (unchanged) ----
#pragma unroll
    for (int mi = 0; mi < 8; ++mi) {
#pragma unroll
        for (int ni = 0; ni < 4; ++ni) {
            const int col = n0 + wc * 64 + ni * 16 + l15;
            float dsum = 0.f;
            if (EPI == 1) dsum = Dv[col] + Dv[512 + col];
#pragma unroll
            for (int r = 0; r < 4; ++r) {
                const int row = m0 + wr * 128 + mi * 16 + lq * 4 + r;
                if (EPI == 0) {
                    Cb[(size_t)row * CN + col] = f2bf(acc[mi][ni][r]);
                } else {
                    const size_t idx = (size_t)row * 512 + col;
                    Cf[idx] = acc[mi][ni][r] + X[idx] * dsum;
                }
            }
        }
    }

    // ---- fused chunk-carry (EPI==0 only), overlaps the store drain ----
    if (EPI == 0) {
        const int dirq = n0 >> 9;            // block-uniform
        const bool evn = ((l15 & 1) == 0);
        const int cidx = ((m0 >> 7) + wr) * 1024;

#define CACC(MI, R, CC) do {                                                  \
            float vo = bf2f(f2bf(acc[MI][ni][R]));                            \
            float vp = __shfl_xor(vo, 1);                                     \
            float vr = evn ? vo : vp;                                         \
            float vi = evn ? vp : vo;                                         \
            wr_ = fmaf(CC.x, vr, fmaf(-CC.y, vi, wr_));                       \
            wi_ = fmaf(CC.x, vi, fmaf(CC.y, vr, wi_));                        \
        } while (0)
#define CSTEP(MI) do {                                                        \
            float wr_ = 0.f, wi_ = 0.f;                                       \
            CACC(MI, 0, c0); CACC(MI, 1, c1);                                 \
            CACC(MI, 2, c2); CACC(MI, 3, c3);                                 \
            float comp = evn ? (t16.x * wr_ - t16.y * wi_)                    \
                             : (t16.x * wi_ + t16.y * wr_);                   \
            csum += comp;                                                     \
            t16 = cmul(t16, A16);                                             \
        } while (0)

#pragma unroll
        for (int ni = 0; ni < 4; ++ni) {
            const int col = n0 + wc * 64 + ni * 16 + l15;
            const int q = col >> 1;
            float2 A1  = make_float2(PW[q * 6 + 0], PW[q * 6 + 1]);
            float2 A4  = make_float2(PW[q * 6 + 2], PW[q * 6 + 3]);
            float2 A16 = make_float2(PW[q * 6 + 4], PW[q * 6 + 5]);
            // P4 = (a^4)^lqp, lqp = dir ? lq : 3-lq  (per-lane select)
            const int lqp = dirq ? lq : 3 - lq;
            float2 A4_2 = cmul(A4, A4);
            float2 A4_3 = cmul(A4_2, A4);
            float2 P4 = (lqp == 0) ? make_float2(1.f, 0.f)
                       : (lqp == 1) ? A4
                       : (lqp == 2) ? A4_2 : A4_3;
            // element coefficients cE[r] = P4 * a^(dir ? r : 3-r)
            float2 c0, c1, c2, c3;
            if (dirq == 0) {
                c3 = P4; c2 = cmul(c3, A1); c1 = cmul(c2, A1); c0 = cmul(c1, A1);
            } else {
                c0 = P4; c1 = cmul(c0, A1); c2 = cmul(c1, A1); c3 = cmul(c2, A1);
            }
            float2 t16 = make_float2(1.f, 0.f);
            float csum = 0.f;
            if (dirq == 0) {   // mi' = 7-s ascending exponent
                CSTEP(7); CSTEP(6); CSTEP(5); CSTEP(4);
                CSTEP(3); CSTEP(2); CSTEP(1); CSTEP(0);
            } else {
                CSTEP(0); CSTEP(1); CSTEP(2); CSTEP(3);
                CSTEP(4); CSTEP(5); CSTEP(6); CSTEP(7);
            }
            // reduce over lq (lanes xor 16, 32 hold same col)
            csum += __shfl_xor(csum, 16);
            csum += __shfl_xor(csum, 32);
            if (lq == 0) CAR[cidx + col] = csum;
        }
#undef CACC
#undef CSTEP
    }
}

// ---------------------------------------------------------------------------
// scan_fin2 = scan_comb folded into scan_final (unchanged from Round 3).
__global__ __launch_bounds__(512)
void scan_fin2(ushort_t* __restrict__ S, const float* __restrict__ abar,
               const float* __restrict__ apow, const float* __restrict__ carry) {
    int b = blockIdx.x, c = blockIdx.y, t = threadIdx.x;
    int dir = t >> 8, p = t & 255;
    float ar = abar[dir * 512 + 2 * p], ai = abar[dir * 512 + 2 * p + 1];
    float pr = apow[dir * 512 + 2 * p], pi = apow[dir * 512 + 2 * p + 1];
    float sr = 0.f, si = 0.f;
    if (dir == 0) {
        for (int cc = 0; cc < c; ++cc) {
            int o = (b * NC + cc) * 1024 + 2 * p;
            float cr0 = carry[o], ci0 = carry[o + 1];
            float nr = fmaf(pr, sr, fmaf(-pi, si, cr0));
            float ni = fmaf(pr, si, fmaf(pi, sr, ci0));
            sr = nr; si = ni;
        }
    } else {
        for (int cc = NC - 1; cc > c; --cc) {
            int o = (b * NC + cc) * 1024 + 512 + 2 * p;
            float cr0 = carry[o], ci0 = carry[o + 1];
            float nr = fmaf(pr, sr, fmaf(-pi, si, cr0));
            float ni = fmaf(pr, si, fmaf(pi, sr, ci0));
            sr = nr; si = ni;
        }
    }
    ushort_t* base = S + ((size_t)b * SEQ + (size_t)c * CH) * 1024
                       + dir * 512 + 2 * p;
    for (int ii = 0; ii < CH; ++ii) {
        int i = dir ? (CH - 1 - ii) : ii;
        unsigned* addr = (unsigned*)(base + (size_t)i * 1024);
        unsigned u = *addr;
        float re = bf2f((ushort_t)(u & 0xffffu));
        float im = bf2f((ushort_t)(u >> 16));
        float nr = fmaf(ar, sr, fmaf(-ai, si, re));
        float ni = fmaf(ar, si, fmaf(ai, sr, im));
        sr = nr; si = ni;
        *addr = ((unsigned)f2bf(si) << 16) | (unsigned)f2bf(sr);
    }
}

// ---------------------------------------------------------------------------
// ws layout (bytes):
//  SB16 : 0           (67,108,864)  [M][1024] bf16 states both dirs
//  X16  : 67,108,864  (33,554,432)  bf16 x   (live through ALL of GEMM1)
//  Bm16 : 100,663,296 (1,048,576)
//  Cm16 : 101,711,872 (1,048,576)
//  abar : 102,760,448 (4,096)
//  apow : 102,764,544 (4,096)
// d_out scratch (dead until GEMM2 writes y; stream-ordered):
//  carry: d_out + 0         (1,048,576)
//  PW   : d_out + 1,048,576 (12,288)
extern "C" void kernel_launch(void* const* d_in, const int* in_sizes, int n_in,
                              void* d_out, int out_size, void* d_ws, size_t ws_size,
                              hipStream_t stream) {
    const float* x   = (const float*)d_in[0];
    const float* Lre = (const float*)d_in[1];
    const float* Lim = (const float*)d_in[2];
    const float* ldt = (const float*)d_in[3];
    const float* Bre = (const float*)d_in[4];
    const float* Bim = (const float*)d_in[5];
    const float* Cre = (const float*)d_in[6];
    const float* Cim = (const float*)d_in[7];
    const float* Dv  = (const float*)d_in[8];
    float* y = (float*)d_out;
    char* ws = (char*)d_ws;

    ushort_t* SB16 = (ushort_t*)(ws);
    ushort_t* X16  = (ushort_t*)(ws + 67108864);
    ushort_t* Bm16 = (ushort_t*)(ws + 100663296);
    ushort_t* Cm16 = (ushort_t*)(ws + 101711872);
    float* abar  = (float*)(ws + 102760448);
    float* apow  = (float*)(ws + 102764544);
    float* carry = (float*)d_out;                       // dead until GEMM2
    float* PW    = (float*)((char*)d_out + 1048576);    // dead until GEMM2

    prep_kernel<<<1024, 256, 0, stream>>>(Lre, Lim, ldt, Bre, Bim, Cre, Cim,
                                          abar, apow, PW, Bm16, Cm16);
    conv_x_kernel<<<16384, 256, 0, stream>>>(x, X16);

    // GEMM1: SB[M][1024] = X16[M][512] * Bm16[1024][512]^T  (+ fused carry)
    gemm_8ph<0, 512, 4><<<512, 512, 0, stream>>>(X16, Bm16, SB16, nullptr,
                                                 nullptr, nullptr, PW, carry);

    dim3 gs(B_SZ, NC);
    scan_fin2<<<gs, 512, 0, stream>>>(SB16, abar, apow, carry);

    // GEMM2: y[M][512] = SB16[M][1024] * Cm16[512][1024]^T + x*(D0+D1)
    gemm_8ph<1, 1024, 2><<<256, 512, 0, stream>>>(SB16, Cm16, nullptr, y,
                                                  x, Dv, nullptr, nullptr);
}